// Round 12
// baseline (51.529 us; speedup 1.0000x reference)
//
#include <hip/hip_runtime.h>
#include <math.h>

#define B_    32
#define C_    64
#define T_    512
#define NROWS (B_ * C_)
#define FEPS  1.1920929e-07f
#define ZSTR  260

// gelu via sigmoid form of the tanh approximation (max abs err ~3e-4)
__device__ __forceinline__ float gelu_fast(float x) {
    float y = fmaf(0.044715f * x * x, x, x);
    float e = __builtin_exp2f(-2.3022808f * y);
    return x * __builtin_amdgcn_rcpf(1.0f + e);
}

// Flattened conv pass: cells (cc, ppw) for window w, iterated over all 128
// threads. Iteration dims (cyI, PI) may exceed the valid set (halo); masks
// use the true (cy, P). ACC: accumulate into z (slow path) vs plain write.
template<bool ACC>
__device__ __forceinline__ void conv_pass(
    const float* __restrict__ rowp, float* __restrict__ zsm,
    const float Wk[5][5], int P, int cy, int bs,
    int cyI, int PI, int w, int tid)
{
    int PwI = PI - (w << 8);
    PwI = PwI > 256 ? 256 : PwI;
    if (PwI <= 0) return;
    const int n = cyI * PwI;
    const unsigned M = 0xFFFFFFFFu / (unsigned)PwI + 1u;   // round-up magic
    for (int i = tid; i < n; i += 128) {
        const int cc  = (int)(((unsigned long long)(unsigned)i * M) >> 32);
        const int ppw = i - cc * PwI;
        const int pp  = ppw + (w << 8);
        const int rb  = bs + cc * P + pp;
        bool hv[5], qv[5];
        #pragma unroll
        for (int d = 0; d < 5; ++d) {
            hv[d] = (unsigned)(cc + d - 2) < (unsigned)cy;
            qv[d] = (unsigned)(pp + d - 2) < (unsigned)P;
        }
        float acc = 0.f;
        #pragma unroll
        for (int dh = 0; dh < 5; ++dh) {
            const int ra = rb + (dh - 2) * P;
            #pragma unroll
            for (int dw = 0; dw < 5; ++dw) {
                unsigned a = (unsigned)(ra + dw - 2);
                a = a > 511u ? 511u : a;
                float val = (hv[dh] && qv[dw]) ? rowp[2 + a] : 0.f;
                acc = fmaf(Wk[dh][dw], val, acc);
            }
        }
        float* zp = zsm + cc * ZSTR + ppw;
        if (ACC) *zp += acc; else *zp = acc;
    }
}

// ---------------- mono kernel: rFFT + top-3 + fold/conv/pools/seq ----------
__global__ __launch_bounds__(128) void mono_kernel(
    const float* __restrict__ feat,
    const float* __restrict__ w0, const float* __restrict__ b0,
    const float* __restrict__ w1, const float* __restrict__ b1,
    const float* __restrict__ w2, const float* __restrict__ b2,
    const float* __restrict__ wpj, const float* __restrict__ bpj,
    const float* __restrict__ wr, const float* __restrict__ br,
    float* __restrict__ avg_out, float* __restrict__ max_out,
    float* __restrict__ seq_out)
{
    __shared__ float rowp[520];          // rowp[2+i] = row[i]
    __shared__ float WeffS[80];
    __shared__ float wtopS[6];
    __shared__ int   itopS[6];
    __shared__ int   ipS[9];             // P[3], cyc[3], base[3]
    __shared__ float bwS[3];
    __shared__ __align__(16) float smem_u[16 * ZSTR];  // FFT bufs overlay z
    float2* FA = reinterpret_cast<float2*>(smem_u);    // [256]
    float2* FB = FA + 256;                             // [256]
    float*  zsm = smem_u;                              // z[cc][p'] cc*ZSTR+p'

    const int tid = threadIdx.x;         // 0..127
    const int lane = tid & 63;
    const int wv = tid >> 6;
    const int r = blockIdx.x;

    // ---- stage row into padded LDS ----
    {
        float4 v = reinterpret_cast<const float4*>(feat + (size_t)r * T_)[tid];
        int bi = 2 + tid * 4;
        rowp[bi + 0] = v.x; rowp[bi + 1] = v.y;
        rowp[bi + 2] = v.z; rowp[bi + 3] = v.w;
    }
    if (tid < 2) rowp[tid] = 0.f;
    if (tid >= 122) rowp[392 + tid] = 0.f;     // 514..519
    if (tid < 80) {
        int i = tid;
        if (i < 75) {
            int k = i / 25, ij = i % 25, ii = ij / 5, jj = ij % 5;
            float w = wpj[2] * w2[k * 25 + ii * 5 + jj];
            if (ii >= 1 && ii <= 3 && jj >= 1 && jj <= 3)
                w += wpj[1] * w1[k * 9 + (ii - 1) * 3 + (jj - 1)];
            if (ii == 2 && jj == 2) w += wpj[0] * w0[k];
            WeffS[i] = w;
        } else if (i == 75) {
            WeffS[75] = wpj[0] * b0[0] + wpj[1] * b1[0] + wpj[2] * b2[0] + bpj[0];
        } else if (i <= 78) {
            WeffS[i] = wr[i - 76];
        } else {
            WeffS[79] = br[0];
        }
    }
    __syncthreads();

    // ---- pack: wave wv owns z_wv[n] = x[4n+2wv] + i x[4n+1+2wv] ----
    {
        float2* Fw = FA + (wv << 7);
        #pragma unroll
        for (int n = lane; n < 128; n += 64)
            Fw[n] = make_float2(rowp[2 + 4 * n + 2 * wv], rowp[3 + 4 * n + 2 * wv]);
    }

    // ---- 7-stage wave-local Stockham 128-pt FFT (no barriers) ----
    {
        float2* src = FA + (wv << 7);
        float2* dst = FB + (wv << 7);
        #pragma unroll
        for (int s = 1; s <= 7; ++s) {
            const int l = 1 << (s - 1);
            const int pl = lane & (l - 1);
            const int i0 = 2 * lane - pl;
            const float rev = (float)pl * (0.5f / (float)l);   // e^{-i pi pl/l}
            const float cw =  __builtin_amdgcn_cosf(rev);
            const float sw = -__builtin_amdgcn_sinf(rev);
            float2 a = src[lane];
            float2 b = src[lane + 64];
            float tr = cw * b.x - sw * b.y;
            float ti = cw * b.y + sw * b.x;
            dst[i0]     = make_float2(a.x + tr, a.y + ti);
            dst[i0 + l] = make_float2(a.x - tr, a.y - ti);
            float2* tmp = src; src = dst; dst = tmp;
        }
    }
    __syncthreads();

    // ---- combine + rfft unpack: bins k1=tid+1, k2=tid+129 ----
    float v[2]; int id[2];
    {
        const float2* Fe = FB;
        const float2* Fo = FB + 128;
        const int k1 = tid + 1;
        const int a = k1 & 127;
        const int b = (128 - a) & 127;
        float2 Fea = Fe[a], Foa = Fo[a], Feb = Fe[b], Fob = Fo[b];
        const float revw = (float)k1 * (1.0f / 256.0f);
        const float cw =  __builtin_amdgcn_cosf(revw);
        const float sw = -__builtin_amdgcn_sinf(revw);
        float wfr = cw * Foa.x - sw * Foa.y, wfi = cw * Foa.y + sw * Foa.x;
        float cfr = cw * Fob.x + sw * Fob.y, cfi = cw * Fob.y - sw * Fob.x;
        const float revu = (float)k1 * (1.0f / 512.0f);
        const float su = __builtin_amdgcn_sinf(revu);
        const float cu = __builtin_amdgcn_cosf(revu);
        #pragma unroll
        for (int q = 0; q < 2; ++q) {
            const float sgn = q ? -1.f : 1.f;
            float Ax = Fea.x + sgn * wfr, Ay = Fea.y + sgn * wfi;
            float Bx = Feb.x + sgn * cfr, By = Feb.y + sgn * cfi;
            float Er = 0.5f * (Ax + Bx);
            float Ei = 0.5f * (Ay - By);
            float Or = 0.5f * (Ay + By);
            float Oi = 0.5f * (Bx - Ax);
            float cth = q ? -su : cu;
            float sth = q ?  cu : su;
            float Fr = Er + cth * Or + sth * Oi;
            float Fi = Ei + cth * Oi - sth * Or;
            v[q] = sqrtf(Fr * Fr + Fi * Fi);
            id[q] = k1 + 128 * q;
        }
    }

    // ---- wave-local top-3 then cross-wave merge ----
    {
        float vals[3]; int idxs[3];
        #pragma unroll
        for (int kk = 0; kk < 3; ++kk) {
            float bv = v[0]; int bi = id[0];
            if (v[1] > bv || (v[1] == bv && id[1] < bi)) { bv = v[1]; bi = id[1]; }
            #pragma unroll
            for (int off = 32; off >= 1; off >>= 1) {
                float ov = __shfl_xor(bv, off, 64);
                int   oi = __shfl_xor(bi, off, 64);
                if (ov > bv || (ov == bv && oi < bi)) { bv = ov; bi = oi; }
            }
            vals[kk] = bv; idxs[kk] = bi;
            #pragma unroll
            for (int q = 0; q < 2; ++q)
                if (id[q] == bi) v[q] = -1e30f;
        }
        if (lane == 0) {
            #pragma unroll
            for (int kk = 0; kk < 3; ++kk) {
                wtopS[wv * 3 + kk] = vals[kk];
                itopS[wv * 3 + kk] = idxs[kk];
            }
        }
    }
    __syncthreads();
    if (tid == 0) {
        float vv[6]; int ii[6];
        #pragma unroll
        for (int q = 0; q < 6; ++q) { vv[q] = wtopS[q]; ii[q] = itopS[q]; }
        float vals[3]; int idxs[3];
        #pragma unroll
        for (int kk = 0; kk < 3; ++kk) {
            float bv = vv[0]; int bi = ii[0];
            #pragma unroll
            for (int q = 1; q < 6; ++q)
                if (vv[q] > bv || (vv[q] == bv && ii[q] < bi)) { bv = vv[q]; bi = ii[q]; }
            vals[kk] = bv; idxs[kk] = bi;
            #pragma unroll
            for (int q = 0; q < 6; ++q)
                if (ii[q] == bi) vv[q] = -1e30f;
        }
        float m = fmaxf(vals[0], fmaxf(vals[1], vals[2]));
        float e0 = expf(vals[0] - m), e1 = expf(vals[1] - m), e2 = expf(vals[2] - m);
        float inv = 1.0f / (e0 + e1 + e2);
        bwS[0] = e0 * inv; bwS[1] = e1 * inv; bwS[2] = e2 * inv;
        #pragma unroll
        for (int kk = 0; kk < 3; ++kk) {
            int fi = idxs[kk];
            int P = T_ / fi;
            P = P < 32 ? 32 : (P > 512 ? 512 : P);
            int cyc = T_ / P;
            ipS[kk] = P; ipS[3 + kk] = cyc; ipS[6 + kk] = T_ - cyc * P;
        }
    }
    __syncthreads();

    const int P0  = __builtin_amdgcn_readfirstlane(ipS[0]);
    const int P1  = __builtin_amdgcn_readfirstlane(ipS[1]);
    const int P2  = __builtin_amdgcn_readfirstlane(ipS[2]);
    const int cy0 = __builtin_amdgcn_readfirstlane(ipS[3]);
    const int cy1 = __builtin_amdgcn_readfirstlane(ipS[4]);
    const int cy2 = __builtin_amdgcn_readfirstlane(ipS[5]);
    const int bs0 = __builtin_amdgcn_readfirstlane(ipS[6]);
    const int bs1 = __builtin_amdgcn_readfirstlane(ipS[7]);
    const int bs2 = __builtin_amdgcn_readfirstlane(ipS[8]);
    const float bw0 = bwS[0], bw1 = bwS[1], bw2 = bwS[2];
    const float beff = WeffS[75], wr0 = WeffS[76], wr1 = WeffS[77],
                wr2 = WeffS[78], bres = WeffS[79];

    int maxP = P0 > P1 ? P0 : P1; maxP = maxP > P2 ? maxP : P2;
    const bool fastp = (P0 == P1) && (P1 == P2);
    const int PkA[3]  = {P0, P1, P2};
    const int cykA[3] = {cy0, cy1, cy2};
    const int bskA[3] = {bs0, bs1, bs2};
    const size_t rT = (size_t)r * T_;

    #pragma unroll 1
    for (int w = 0; w < 2; ++w) {
        const int wbase = w << 8;
        if (wbase < maxP) {
            if (fastp) {
                // identical folds: single conv with summed weights, plain write
                float Wk[5][5];
                #pragma unroll
                for (int ij = 0; ij < 25; ++ij)
                    (&Wk[0][0])[ij] = WeffS[ij] + WeffS[25 + ij] + WeffS[50 + ij];
                conv_pass<false>(rowp, zsm, Wk, P0, cy0, bs0, cy0, P0, w, tid);
                __syncthreads();
            } else {
                // zero-init window, then 3 accumulate passes (+2 halo ranges)
                #pragma unroll
                for (int j = 0; j < 8; ++j) {
                    int idx = tid + (j << 7);          // 0..1023
                    int cc = idx >> 6, p4 = idx & 63;
                    *reinterpret_cast<float4*>(zsm + cc * ZSTR + (p4 << 2)) =
                        make_float4(0.f, 0.f, 0.f, 0.f);
                }
                __syncthreads();
                #pragma unroll 1
                for (int k = 0; k < 3; ++k) {
                    float Wk[5][5];
                    #pragma unroll
                    for (int ij = 0; ij < 25; ++ij)
                        (&Wk[0][0])[ij] = WeffS[k * 25 + ij];
                    const int P = PkA[k], cyk = cykA[k], bsk = bskA[k];
                    int cyI = cyk + 2; cyI = cyI > 16 ? 16 : cyI;
                    int PI  = P + 2;   PI  = PI > 512 ? 512 : PI;
                    conv_pass<true>(rowp, zsm, Wk, P, cyk, bsk, cyI, PI, w, tid);
                    __syncthreads();
                }
            }
        }

        // ---- pools + seq for the two 128-wide chunks of this window ----
        #pragma unroll 1
        for (int half = 0; half < 2; ++half) {
            const int pc = wbase + (half << 7);
            const int p = pc + tid;
            if (pc >= maxP) {
                avg_out[rT + p] = 0.f;
                max_out[rT + p] = 0.f;
                seq_out[rT + p] = 0.f;
                continue;
            }
            int c0 = (P0 > pc) ? cy0 : 0;
            int c1 = (P1 > pc) ? cy1 : 0;
            int c2 = (P2 > pc) ? cy2 : 0;
            int cymaxc = c0 > c1 ? c0 : c1; cymaxc = cymaxc > c2 ? cymaxc : c2;

            float avg_num = 0.f, den = 0.f, mx = -3.402823466e38f;
            float s0 = 0.f, s1 = 0.f, s2 = 0.f;
            int anyv = 0;
            const int pl0 = (p < P0), pl1 = (p < P1), pl2 = (p < P2);
            #pragma unroll 1
            for (int cc = 0; cc < cymaxc; ++cc) {
                int m0 = (cc < cy0) & pl0;
                int m1 = (cc < cy1) & pl1;
                int m2 = (cc < cy2) & pl2;
                float zr = zsm[cc * ZSTR + (p - wbase)];
                unsigned a0 = (unsigned)(bs0 + cc * P0 + p); a0 = a0 > 511u ? 511u : a0;
                unsigned a1 = (unsigned)(bs1 + cc * P1 + p); a1 = a1 > 511u ? 511u : a1;
                unsigned a2 = (unsigned)(bs2 + cc * P2 + p); a2 = a2 > 511u ? 511u : a2;
                float x0v = m0 ? rowp[2 + a0] : 0.f;
                float x1v = m1 ? rowp[2 + a1] : 0.f;
                float x2v = m2 ? rowp[2 + a2] : 0.f;
                float res = fmaf(wr0, x0v, fmaf(wr1, x1v, fmaf(wr2, x2v, bres)));
                float zv = gelu_fast(zr + beff) + res;
                int mm = m0 | m1 | m2;
                avg_num += mm ? zv : 0.f;       // select (garbage-z safe)
                den     += mm ? 1.f : 0.f;
                mx = mm ? fmaxf(mx, zv) : mx;
                anyv |= mm;
                s0 += x0v; s1 += x1v; s2 += x2v;
            }
            float avg = avg_num / (den + FEPS);
            float mpool = anyv ? mx : 0.f;
            float seq = 0.f;
            seq = fmaf(bw0, pl0 ? s0 / ((float)cy0 + FEPS) : 0.f, seq);
            seq = fmaf(bw1, pl1 ? s1 / ((float)cy1 + FEPS) : 0.f, seq);
            seq = fmaf(bw2, pl2 ? s2 / ((float)cy2 + FEPS) : 0.f, seq);

            avg_out[rT + p] = avg;
            max_out[rT + p] = mpool;
            seq_out[rT + p] = seq;
        }
        __syncthreads();   // z window reuse fence
    }
}

// ---------- fuse GEMM + gelu (unchanged from R11) ----------
__global__ __launch_bounds__(256) void fuse_kernel(
    const float* __restrict__ avgb, const float* __restrict__ maxb,
    const float* __restrict__ seqb,
    const float* __restrict__ wf, const float* __restrict__ bfu,
    float* __restrict__ out)
{
    __shared__ float wT[64][70];
    __shared__ float Bt[64][40];
    const int tid = threadIdx.x;
    const int b = blockIdx.y;
    const int tt0 = blockIdx.x * 32;
    const int og = tid >> 3;
    const int tg = tid & 7;
    const int o0 = og * 2;
    const int t0 = tg * 4;

    float acc[2][4];
    #pragma unroll
    for (int i = 0; i < 2; ++i)
        #pragma unroll
        for (int j = 0; j < 4; ++j) acc[i][j] = 0.f;

    const float* srcs[3] = {avgb, maxb, seqb};
    for (int g = 0; g < 3; ++g) {
        const float* __restrict__ src = srcs[g];
        #pragma unroll
        for (int it = 0; it < 2; ++it) {
            int idx = tid + it * 256;
            int c = idx >> 3, t4 = idx & 7;
            float4 vv = reinterpret_cast<const float4*>(
                            &src[(b * 64 + c) * 512 + tt0])[t4];
            *reinterpret_cast<float4*>(&Bt[c][t4 * 4]) = vv;
        }
        #pragma unroll
        for (int it = 0; it < 16; ++it) {
            int i = tid + it * 256;
            int c = i & 63, o = i >> 6;
            wT[c][o] = wf[o * 192 + g * 64 + c];
        }
        __syncthreads();
        for (int c = 0; c < 64; ++c) {
            float2 wv = *reinterpret_cast<const float2*>(&wT[c][o0]);
            float4 bv = *reinterpret_cast<const float4*>(&Bt[c][t0]);
            const float wa[2] = {wv.x, wv.y};
            const float ba[4] = {bv.x, bv.y, bv.z, bv.w};
            #pragma unroll
            for (int i = 0; i < 2; ++i)
                #pragma unroll
                for (int j = 0; j < 4; ++j)
                    acc[i][j] = fmaf(wa[i], ba[j], acc[i][j]);
        }
        __syncthreads();
    }
    #pragma unroll
    for (int i = 0; i < 2; ++i) {
        float bias = bfu[o0 + i];
        float4 o4;
        o4.x = gelu_fast(acc[i][0] + bias);
        o4.y = gelu_fast(acc[i][1] + bias);
        o4.z = gelu_fast(acc[i][2] + bias);
        o4.w = gelu_fast(acc[i][3] + bias);
        *reinterpret_cast<float4*>(
            &out[(b * 64 + (o0 + i)) * 512 + tt0 + t0]) = o4;
    }
}

extern "C" void kernel_launch(void* const* d_in, const int* in_sizes, int n_in,
                              void* d_out, int out_size, void* d_ws, size_t ws_size,
                              hipStream_t stream) {
    const float* feat = (const float*)d_in[0];
    const float* w0  = (const float*)d_in[1];
    const float* b0  = (const float*)d_in[2];
    const float* w1  = (const float*)d_in[3];
    const float* b1  = (const float*)d_in[4];
    const float* w2  = (const float*)d_in[5];
    const float* b2  = (const float*)d_in[6];
    const float* wpj = (const float*)d_in[7];
    const float* bpj = (const float*)d_in[8];
    const float* wr  = (const float*)d_in[9];
    const float* br  = (const float*)d_in[10];
    const float* wf  = (const float*)d_in[11];
    const float* bfu = (const float*)d_in[12];

    float* ws = (float*)d_ws;
    float* avgb = ws;
    float* maxb = ws + (size_t)NROWS * T_;
    float* seqb = ws + 2 * (size_t)NROWS * T_;

    mono_kernel<<<NROWS, 128, 0, stream>>>(feat, w0, b0, w1, b1, w2, b2,
                                           wpj, bpj, wr, br, avgb, maxb, seqb);
    fuse_kernel<<<dim3(16, 32), 256, 0, stream>>>(avgb, maxb, seqb, wf, bfu,
                                                  (float*)d_out);
}